// Round 6
// baseline (96.267 us; speedup 1.0000x reference)
//
#include <hip/hip_runtime.h>

// YOLOX head decode, fused single-launch, TP=64, pipelined 2 tiles/block.
// (N, A*85, H, W) -> (N, A*H*W, 85) with sigmoid on obj/cls and fused box
// decode on channels 0..3 (wave-0 shuffle exchange, no separate fixup
// phase). Streaming transpose: coalesced float4 reads -> regs (MLP=6) ->
// sigmoid/decode -> LDS [pos][85] -> coalesced float4 nt-writes of the
// contiguous output region. Tile i+1's loads are issued before tile i's
// write phase (T14 issue-early). Plain loads (L3-allocate: 254 MB input
// set is re-read every replay), nontemporal stores (touch-once output).

typedef float v4f __attribute__((ext_vector_type(4)));

#define NATT 85
#define TP 64              // positions per tile
#define TOTAL_ROWS 25200
#define NIT 6              // ceil(85/16) plane-iterations per thread

__device__ __forceinline__ float sigmf(float v) {
    return 1.0f / (1.0f + __expf(-v));
}

template <int LVL> struct G {
    static constexpr int   H  = (LVL == 0) ? 20 : (LVL == 1) ? 40 : 80;
    static constexpr int   W  = H;
    static constexpr int   HW = H * W;
    static constexpr float S  = (LVL == 0) ? 32.f : (LVL == 1) ? 16.f : 8.f;
    static constexpr int   OUT_BASE = (LVL == 0) ? 0 : (LVL == 1) ? 1200 : 6000;
    static constexpr int   C  = (HW + TP - 1) / TP;  // chunks per (n,a): 7/25/100
};

struct Tile {
    const float* inp;
    int pos0, valid, a, n;
};

template <int LVL>
__device__ __forceinline__ Tile mk_tile(const float* __restrict__ in, int id) {
    Tile t;
    const int chunk = id % G<LVL>::C;
    const int ta    = id / G<LVL>::C;
    t.a     = ta % 3;
    t.n     = ta / 3;
    t.pos0  = chunk * TP;
    const int rem = G<LVL>::HW - t.pos0;
    t.valid = rem < TP ? rem : TP;
    t.inp   = in + ((size_t)t.n * 255 + (size_t)t.a * NATT) * G<LVL>::HW + t.pos0;
    return t;
}

template <int LVL>
__device__ __forceinline__ void issue(const Tile& t, v4f r[NIT], int tid) {
    const int p  = (tid & 15) * 4;
    const int k0 = tid >> 4;
#pragma unroll
    for (int it = 0; it < NIT; ++it) r[it] = v4f{0.f, 0.f, 0.f, 0.f};
    if (p < t.valid) {
#pragma unroll
        for (int it = 0; it < NIT; ++it) {
            const int kk = k0 + it * 16;
            if (kk < NATT)
                r[it] = *reinterpret_cast<const v4f*>(t.inp + (size_t)kk * G<LVL>::HW + p);
        }
    }
}

template <int LVL>
__device__ __forceinline__ void scatter(const Tile& t, v4f r[NIT], float* lds, int tid) {
    const int m   = tid & 15;
    const int p   = m * 4;
    const int k0  = tid >> 4;
    const bool act = (p < t.valid);

    if (tid < 64) {
        // wave 0 holds planes 0..3 at it=0: fused box decode.
        // partner lane = tid ^ 32  (k0 0<->2, 1<->3)
        v4f mine = r[0];
        v4f part;
        part.x = __shfl_xor(mine.x, 32);
        part.y = __shfl_xor(mine.y, 32);
        part.z = __shfl_xor(mine.z, 32);
        part.w = __shfl_xor(mine.w, 32);

        const int a = t.a;
        const float wa = (a == 0) ? ((LVL == 0) ? 116.f : (LVL == 1) ? 30.f : 10.f)
                       : (a == 1) ? ((LVL == 0) ? 156.f : (LVL == 1) ? 62.f : 16.f)
                                  : ((LVL == 0) ? 373.f : (LVL == 1) ? 59.f : 33.f);
        const float ha = (a == 0) ? ((LVL == 0) ?  90.f : (LVL == 1) ? 61.f : 13.f)
                       : (a == 1) ? ((LVL == 0) ? 198.f : (LVL == 1) ? 45.f : 30.f)
                                  : ((LVL == 0) ? 326.f : (LVL == 1) ? 119.f : 23.f);
        const float dim = (k0 & 1) ? ha : wa;           // even k0 -> width, odd -> height
        const float sgn = (k0 & 2) ? 0.5f : -0.5f;      // k0 0,1 -> x1y1; k0 2,3 -> x2y2

        if (act) {
#pragma unroll
            for (int j = 0; j < 4; ++j) {
                const int gp = t.pos0 + p + j;
                const int y  = gp / G<LVL>::W;
                const int x  = gp - y * G<LVL>::W;
                const float coord = (k0 & 1) ? (float)y : (float)x;
                const float pc = (k0 & 2) ? part[j] : mine[j];  // center pred
                const float pe = (k0 & 2) ? mine[j] : part[j];  // size pred
                const float c  = (pc + coord) * G<LVL>::S;
                const float e  = __expf(pe) * dim;
                lds[(p + j) * NATT + k0] = c + sgn * e;
            }
            // remaining planes of wave 0: kk = k0+16*it >= 16 -> sigmoid
#pragma unroll
            for (int it = 1; it < NIT; ++it) {
                const int kk = k0 + it * 16;                    // <= 83, always valid
                v4f v = r[it];
                v.x = sigmf(v.x); v.y = sigmf(v.y);
                v.z = sigmf(v.z); v.w = sigmf(v.w);
                lds[(p + 0) * NATT + kk] = v.x;
                lds[(p + 1) * NATT + kk] = v.y;
                lds[(p + 2) * NATT + kk] = v.z;
                lds[(p + 3) * NATT + kk] = v.w;
            }
        }
    } else {
        // waves 1..3: kk >= 4 always -> plain sigmoid
        if (act) {
#pragma unroll
            for (int it = 0; it < NIT; ++it) {
                const int kk = k0 + it * 16;
                if (kk < NATT) {
                    v4f v = r[it];
                    v.x = sigmf(v.x); v.y = sigmf(v.y);
                    v.z = sigmf(v.z); v.w = sigmf(v.w);
                    lds[(p + 0) * NATT + kk] = v.x;
                    lds[(p + 1) * NATT + kk] = v.y;
                    lds[(p + 2) * NATT + kk] = v.z;
                    lds[(p + 3) * NATT + kk] = v.w;
                }
            }
        }
    }
}

template <int LVL>
__device__ __forceinline__ void write_out(const Tile& t, const float* lds,
                                          float* __restrict__ out, int tid) {
    const size_t row0 = (size_t)t.n * TOTAL_ROWS + G<LVL>::OUT_BASE
                      + (size_t)t.a * G<LVL>::HW + t.pos0;
    float* op = out + row0 * NATT;
    const int nfl = t.valid * NATT;        // 5440 or 1360, divisible by 4
    for (int i = tid * 4; i + 3 < nfl; i += 1024) {
        __builtin_nontemporal_store(*reinterpret_cast<const v4f*>(lds + i),
                                    reinterpret_cast<v4f*>(op + i));
    }
}

template <int LVL>
__device__ __forceinline__ void process2(const float* __restrict__ in,
                                         float* __restrict__ out,
                                         int pair, float* lds) {
    const int tid = threadIdx.x;
    const Tile t0 = mk_tile<LVL>(in, 2 * pair);
    const Tile t1 = mk_tile<LVL>(in, 2 * pair + 1);
    v4f r0[NIT], r1[NIT];

    issue<LVL>(t0, r0, tid);
    scatter<LVL>(t0, r0, lds, tid);
    __syncthreads();
    issue<LVL>(t1, r1, tid);           // loads in flight under t0's write drain
    write_out<LVL>(t0, lds, out, tid);
    __syncthreads();                   // all LDS reads done before overwrite
    scatter<LVL>(t1, r1, lds, tid);
    __syncthreads();
    write_out<LVL>(t1, lds, out, tid);
}

// Pair counts: lvl2 = 9600/2 = 4800, lvl1 = 2400/2 = 1200, lvl0 = 672/2 = 336.
// Total 6336 blocks, biggest level first.
__global__ __launch_bounds__(256) void yolox_fused(const float* __restrict__ in0,
                                                   const float* __restrict__ in1,
                                                   const float* __restrict__ in2,
                                                   float* __restrict__ out) {
    __shared__ float lds[TP * NATT];   // 21760 B
    const int bid = blockIdx.x;
    if (bid < 4800) {
        process2<2>(in2, out, bid, lds);
    } else if (bid < 6000) {
        process2<1>(in1, out, bid - 4800, lds);
    } else {
        process2<0>(in0, out, bid - 6000, lds);
    }
}

extern "C" void kernel_launch(void* const* d_in, const int* in_sizes, int n_in,
                              void* d_out, int out_size, void* d_ws, size_t ws_size,
                              hipStream_t stream) {
    const float* in0 = (const float*)d_in[0];  // (32,255,20,20)
    const float* in1 = (const float*)d_in[1];  // (32,255,40,40)
    const float* in2 = (const float*)d_in[2];  // (32,255,80,80)
    float* out = (float*)d_out;                // (32,25200,85)

    yolox_fused<<<dim3(6336), dim3(256), 0, stream>>>(in0, in1, in2, out);
}

// Round 7
// 93.148 us; speedup vs baseline: 1.0335x; 1.0335x over previous
//
#include <hip/hip_runtime.h>

// YOLOX head decode, fused single-launch, TP=64, MLP-staged loads.
// (R5 configuration — best measured: 91.4 us = 95% of the 6.29 TB/s
// mixed-stream ceiling. R3's TP=128 and R6's 2-tile pipeline both
// regressed by trading occupancy/granularity for intra-block overlap.)
//
// (N, A*85, H, W) -> (N, A*H*W, 85) with sigmoid on obj/cls and box decode
// on channels 0..3. Streaming transpose: coalesced float4 reads per
// channel-plane -> registers (all ~6 planes in flight per thread) ->
// sigmoid -> LDS [pos][85] -> coalesced float4 writes of the contiguous
// output region. Plain loads (allocate in 256 MiB Infinity Cache; inputs
// are re-read every graph replay), nontemporal stores (touch-once output,
// don't evict the inputs).

typedef float v4f __attribute__((ext_vector_type(4)));

#define NATT 85
#define TP 64              // positions per block
#define TOTAL_ROWS 25200
#define NIT 6              // ceil(85/16) plane-iterations per thread

__device__ __forceinline__ float sigmf(float v) {
    return 1.0f / (1.0f + __expf(-v));
}

template <int LVL>
__device__ __forceinline__ void process(const float* __restrict__ in,
                                        float* __restrict__ out,
                                        int id, float* lds) {
    constexpr int   H  = (LVL == 0) ? 20 : (LVL == 1) ? 40 : 80;
    constexpr int   W  = H;
    constexpr int   HW = H * W;
    constexpr float S  = (LVL == 0) ? 32.f : (LVL == 1) ? 16.f : 8.f;
    constexpr int   OUT_BASE = (LVL == 0) ? 0 : (LVL == 1) ? 1200 : 6000;
    constexpr int   C  = (HW + TP - 1) / TP;   // chunks per (n,a): 7 / 25 / 100

    const int tid   = threadIdx.x;     // 256 threads = 4 waves
    const int chunk = id % C;
    const int ta    = id / C;
    const int a     = ta % 3;          // anchor
    const int n     = ta / 3;          // batch

    const int pos0  = chunk * TP;
    const int valid = (HW - pos0 < TP) ? (HW - pos0) : TP;  // 64, or 16 (lvl0 tail)

    // input plane base for (n, anchor a, k=0) at this position chunk
    const float* inp = in + ((size_t)n * 255 + (size_t)a * NATT) * HW + pos0;

    // ---- load phase: stage all plane loads first (MLP=6), then scatter ----
    const int m  = tid & 15;       // which float4 within the 64-pos chunk
    const int p  = m * 4;          // position offset of this vec
    const int k0 = tid >> 4;       // first plane of this thread
    const bool act = (p < valid);  // valid is always a multiple of 4

    v4f r[NIT];
#pragma unroll
    for (int it = 0; it < NIT; ++it) {
        const int kk = k0 + it * 16;
        if (kk < NATT && act) {
            r[it] = *reinterpret_cast<const v4f*>(inp + (size_t)kk * HW + p);
        }
    }
#pragma unroll
    for (int it = 0; it < NIT; ++it) {
        const int kk = k0 + it * 16;
        if (kk < NATT && act) {
            v4f v = r[it];
            if (kk >= 4) {
                v.x = sigmf(v.x); v.y = sigmf(v.y);
                v.z = sigmf(v.z); v.w = sigmf(v.w);
            }
            lds[(p + 0) * NATT + kk] = v.x;
            lds[(p + 1) * NATT + kk] = v.y;
            lds[(p + 2) * NATT + kk] = v.z;
            lds[(p + 3) * NATT + kk] = v.w;
        }
    }
    __syncthreads();

    // ---- fix-up phase: decode boxes in place (one lane per position) ----
    if (tid < TP && tid < valid) {
        const int gp = pos0 + tid;
        const int y  = gp / W;
        const int x  = gp - y * W;
        const float wa = (a == 0) ? ((LVL == 0) ? 116.f : (LVL == 1) ? 30.f : 10.f)
                       : (a == 1) ? ((LVL == 0) ? 156.f : (LVL == 1) ? 62.f : 16.f)
                                  : ((LVL == 0) ? 373.f : (LVL == 1) ? 59.f : 33.f);
        const float ha = (a == 0) ? ((LVL == 0) ?  90.f : (LVL == 1) ? 61.f : 13.f)
                       : (a == 1) ? ((LVL == 0) ? 198.f : (LVL == 1) ? 45.f : 30.f)
                                  : ((LVL == 0) ? 326.f : (LVL == 1) ? 119.f : 23.f);
        const float p0 = lds[tid * NATT + 0];
        const float p1 = lds[tid * NATT + 1];
        const float p2 = lds[tid * NATT + 2];
        const float p3 = lds[tid * NATT + 3];
        // (p0-0.5)*S + (x+0.5)*S == (p0+x)*S
        const float xc = (p0 + (float)x) * S;
        const float yc = (p1 + (float)y) * S;
        const float w  = __expf(p2) * wa;
        const float h  = __expf(p3) * ha;
        lds[tid * NATT + 0] = xc - 0.5f * w;
        lds[tid * NATT + 1] = yc - 0.5f * h;
        lds[tid * NATT + 2] = xc + 0.5f * w;
        lds[tid * NATT + 3] = yc + 0.5f * h;
    }
    __syncthreads();

    // ---- write phase: output region is valid*85 contiguous floats ----
    const size_t row0 = (size_t)n * TOTAL_ROWS + OUT_BASE + (size_t)a * HW + pos0;
    float* op = out + row0 * NATT;
    const int nfl = valid * NATT;          // 5440 or 1360, both divisible by 4
    for (int i = tid * 4; i + 3 < nfl; i += 1024) {
        __builtin_nontemporal_store(*reinterpret_cast<const v4f*>(lds + i),
                                    reinterpret_cast<v4f*>(op + i));
    }
}

// Block counts: lvl2 = 100*3*32 = 9600, lvl1 = 25*3*32 = 2400,
// lvl0 = 7*3*32 = 672. Total 12672. Biggest level first.
__global__ __launch_bounds__(256) void yolox_fused(const float* __restrict__ in0,
                                                   const float* __restrict__ in1,
                                                   const float* __restrict__ in2,
                                                   float* __restrict__ out) {
    __shared__ float lds[TP * NATT];   // 21760 B, shared by all paths
    const int bid = blockIdx.x;
    if (bid < 9600) {
        process<2>(in2, out, bid, lds);
    } else if (bid < 12000) {
        process<1>(in1, out, bid - 9600, lds);
    } else {
        process<0>(in0, out, bid - 12000, lds);
    }
}

extern "C" void kernel_launch(void* const* d_in, const int* in_sizes, int n_in,
                              void* d_out, int out_size, void* d_ws, size_t ws_size,
                              hipStream_t stream) {
    const float* in0 = (const float*)d_in[0];  // (32,255,20,20)
    const float* in1 = (const float*)d_in[1];  // (32,255,40,40)
    const float* in2 = (const float*)d_in[2];  // (32,255,80,80)
    float* out = (float*)d_out;                // (32,25200,85)

    yolox_fused<<<dim3(12672), dim3(256), 0, stream>>>(in0, in1, in2, out);
}